// Round 6
// baseline (127.828 us; speedup 1.0000x reference)
//
#include <hip/hip_runtime.h>
#include <hip/hip_bf16.h>

#if defined(__has_builtin)
#if __has_builtin(__builtin_amdgcn_exp2f)
#define EXP2F __builtin_amdgcn_exp2f
#endif
#if __has_builtin(__builtin_amdgcn_rcpf)
#define RCPF __builtin_amdgcn_rcpf
#endif
#endif
#ifndef EXP2F
#define EXP2F exp2f
#endif
#ifndef RCPF
#define RCPF(x) (1.0f / (x))
#endif

// Sizes (fixed by the problem)
#define B_  8
#define Q_  256
#define K_  1024
#define D_  256
#define H_  128
#define DV_ 128

#define CSL 2.8853900817779268f   // 2*log2(e)
#define L2E 1.4426950408889634f   // log2(e)

// Workspace layout (floats). ~5.25 MB used; harness poisons all 256 MiB of
// d_ws each timed iter (~42 us fill, fixed overhead we cannot remove).
#define QE_OFF   0                // qE   [B*Q][H]              = 262144
#define KE_OFF   262144           // kET2 [B][64 p][K] float2   = 1048576 floats
#define WPK_OFF  1310720          // wpk  [64] float4           = 256

// ---------------------------------------------------------------------------
// proj_kernel: 320 blocks, 64 rows x 64 cols per block, 256 threads, 4x4
// micro-tile -> all-b128 LDS reads. blk 0..63 = Q (32 rowtiles x 2 colhalves),
// blk 64..319 = K (128 rowtiles x 2 colhalves).
// Epilogue: exp2(CSL*x); Q rows -> qE row-major; K rows -> kET2[b][p][k]
// float2 = (E_{2p}, E_{2p+1}).
// ---------------------------------------------------------------------------
__global__ __launch_bounds__(256) void proj_kernel(
    const float* __restrict__ queries, const float* __restrict__ keys,
    const float* __restrict__ Wq, const float* __restrict__ Wk,
    const float* __restrict__ w_v,
    float* __restrict__ qE, float2* __restrict__ kET2, float* __restrict__ wpk)
{
    __shared__ __align__(16) float As[64][68];   // [d][row], pad 68
    __shared__ __align__(16) float Ws[64][64];   // [d][col]

    const int tid = threadIdx.x;
    const int blk = blockIdx.x;
    const bool isQ = blk < 64;
    const int t = isQ ? blk : (blk - 64);
    const int rowtile = t >> 1;
    const int cbase = (t & 1) * 64;
    const int row0 = rowtile * 64;
    const float* A = isQ ? (queries + row0 * D_) : (keys + row0 * D_);
    const float* W = isQ ? Wq : Wk;

    float acc[4][4];
#pragma unroll
    for (int i = 0; i < 4; i++)
#pragma unroll
        for (int j = 0; j < 4; j++) acc[i][j] = 0.f;

    const int lr  = tid & 63;          // A-stage row
    const int ldb = (tid >> 6) * 16;   // A-stage d base
    const int r4  = (tid >> 4) * 4;    // compute row base 0..60
    const int c4  = (tid & 15) * 4;    // compute col base 0..60

    for (int d0 = 0; d0 < D_; d0 += 64) {
        // stage A transposed: As[d][row]
#pragma unroll
        for (int j = 0; j < 4; j++) {
            const float4 a = *(const float4*)&A[lr * D_ + d0 + ldb + j * 4];
            As[ldb + j * 4 + 0][lr] = a.x;
            As[ldb + j * 4 + 1][lr] = a.y;
            As[ldb + j * 4 + 2][lr] = a.z;
            As[ldb + j * 4 + 3][lr] = a.w;
        }
        // stage W: 64 d x 64 cols
#pragma unroll
        for (int l = 0; l < 4; l++) {
            const int idx = tid + l * 256;
            const int rr = idx >> 4, cc = (idx & 15) * 4;
            *(float4*)&Ws[rr][cc] = *(const float4*)&W[(d0 + rr) * H_ + cbase + cc];
        }
        __syncthreads();
#pragma unroll 4
        for (int d = 0; d < 64; d++) {
            const float4 a4 = *(const float4*)&As[d][r4];
            const float4 w4 = *(const float4*)&Ws[d][c4];
            const float ar[4] = {a4.x, a4.y, a4.z, a4.w};
#pragma unroll
            for (int i = 0; i < 4; i++) {
                acc[i][0] = fmaf(ar[i], w4.x, acc[i][0]);
                acc[i][1] = fmaf(ar[i], w4.y, acc[i][1]);
                acc[i][2] = fmaf(ar[i], w4.z, acc[i][2]);
                acc[i][3] = fmaf(ar[i], w4.w, acc[i][3]);
            }
        }
        __syncthreads();
    }

#pragma unroll
    for (int i = 0; i < 4; i++) {
        float e[4];
#pragma unroll
        for (int j = 0; j < 4; j++) e[j] = EXP2F(CSL * acc[i][j]);
        const int row = row0 + r4 + i;
        if (isQ) {
            *(float4*)&qE[row * H_ + cbase + c4] = make_float4(e[0], e[1], e[2], e[3]);
        } else {
            const int b = row >> 10, k = row & 1023;   // 64-row tiles never cross b
            const int p0 = (cbase + c4) >> 1;          // h-pair index, even c4 -> 2 pairs
            kET2[(size_t)(b * 64 + p0) * K_ + k]     = make_float2(e[0], e[1]);
            kET2[(size_t)(b * 64 + p0 + 1) * K_ + k] = make_float2(e[2], e[3]);
        }
    }

    if (blk == 0 && tid < 64) {
        const float w1 = -2.0f * L2E * w_v[2 * tid];
        const float w2 = -2.0f * L2E * w_v[2 * tid + 1];
        *(float4*)&wpk[tid * 4] = make_float4(w1, w2, w1 + w2, 0.f);
    }
}

// ---------------------------------------------------------------------------
// attn_kernel: 1024 blocks x 512 threads; b = blockIdx.x & 7 (interleaved so
// the ~4 co-resident blocks/CU come from different batches -> vl-balanced).
// 2 q-rows per block, 2 k per thread (one dwordx4 of kET2 = 2h x 2k).
// Masked-k skip (k >= vl waves idle) + AV k-loop clamp. Exact.
// h-pairing: w1/(1+x1)+w2/(1+x2) = [(w1+w2)+w1*x2+w2*x1]/[(1+x1)(1+x2)].
// ---------------------------------------------------------------------------
__global__ __launch_bounds__(512, 8) void attn_kernel(
    const float* __restrict__ qE,       // [B*Q][H] = e^{2q}
    const float2* __restrict__ kET2,    // [B][64][K] = (e^{2k}) h-pairs
    const float* __restrict__ values,   // [B][K][DV]
    const int*   __restrict__ valid_lens,
    const float* __restrict__ wpk,      // [64] float4 (w1,w2,w1+w2,0)
    float* __restrict__ out)            // [B][Q][DV]
{
    __shared__ __align__(16) float sc[K_][2];        // 8 KB p-values (q0,q1)
    __shared__ __align__(16) float red[16][2][128];  // 16 KB AV reduction
    __shared__ __align__(16) float psum[8][2];
    __shared__ float rl[2];

    const int tid = threadIdx.x;
    const int b  = blockIdx.x & 7;
    const int q0 = (blockIdx.x >> 3) * 2;
    const int vl = valid_lens[b];

    const float* q0p = qE + (b * Q_ + q0) * H_;
    const float* q1p = q0p + H_;
    const int k0 = tid * 2;

    float ac00 = 0.f, ac01 = 0.f, ac10 = 0.f, ac11 = 0.f;  // [q][k]

    if (k0 < vl) {
        const float4* kp = (const float4*)kET2 + (size_t)(b * 64) * 512 + tid;
#pragma unroll 4
        for (int p = 0; p < 64; p++) {
            const float4 v  = kp[(size_t)p * 512];   // (h1k0, h2k0, h1k1, h2k1)
            const float4 wp = *(const float4*)&wpk[p * 4];
            const float2 qa = *(const float2*)&q0p[2 * p];
            const float2 qb = *(const float2*)&q1p[2 * p];
            {   // q row 0
                const float x10 = qa.x * v.x, x20 = qa.y * v.y;
                const float x11 = qa.x * v.z, x21 = qa.y * v.w;
                const float e0 = x10 + 1.f, e1 = x11 + 1.f;
                const float d0 = fmaf(e0, x20, e0), d1 = fmaf(e1, x21, e1);
                float n0 = fmaf(wp.y, x10, wp.z); n0 = fmaf(wp.x, x20, n0);
                float n1 = fmaf(wp.y, x11, wp.z); n1 = fmaf(wp.x, x21, n1);
                ac00 = fmaf(n0, RCPF(d0), ac00);
                ac01 = fmaf(n1, RCPF(d1), ac01);
            }
            {   // q row 1
                const float x10 = qb.x * v.x, x20 = qb.y * v.y;
                const float x11 = qb.x * v.z, x21 = qb.y * v.w;
                const float e0 = x10 + 1.f, e1 = x11 + 1.f;
                const float d0 = fmaf(e0, x20, e0), d1 = fmaf(e1, x21, e1);
                float n0 = fmaf(wp.y, x10, wp.z); n0 = fmaf(wp.x, x20, n0);
                float n1 = fmaf(wp.y, x11, wp.z); n1 = fmaf(wp.x, x21, n1);
                ac10 = fmaf(n0, RCPF(d0), ac10);
                ac11 = fmaf(n1, RCPF(d1), ac11);
            }
        }
    }

    // ---- exp + mask + row sums ----
    const bool v0 = k0 < vl, v1 = (k0 + 1) < vl;
    const float p00 = v0 ? EXP2F(ac00) : 0.f;   // (q0,k0)
    const float p10 = v0 ? EXP2F(ac10) : 0.f;   // (q1,k0)
    const float p01 = v1 ? EXP2F(ac01) : 0.f;   // (q0,k1)
    const float p11 = v1 ? EXP2F(ac11) : 0.f;   // (q1,k1)
    *(float4*)&sc[k0][0] = make_float4(p00, p10, p01, p11);

    float s0 = p00 + p01, s1 = p10 + p11;
#pragma unroll
    for (int sh = 32; sh > 0; sh >>= 1) {
        s0 += __shfl_xor(s0, sh);
        s1 += __shfl_xor(s1, sh);
    }
    const int lane = tid & 63, w = tid >> 6;
    if (lane == 0) { psum[w][0] = s0; psum[w][1] = s1; }
    __syncthreads();
    if (tid < 2) {
        float tsum = 0.f;
#pragma unroll
        for (int ww = 0; ww < 8; ww++) tsum += psum[ww][tid];
        rl[tid] = RCPF(tsum);
    }

    // ---- AV: thread = (kc 0..15, vg 0..31), k-loop clamped to vl ----
    const int vg = (tid & 31) * 4;
    const int kc = tid >> 5;                    // 0..15
    const float* vb = values + (size_t)b * (K_ * DV_) + vg;
    float av[2][4];
#pragma unroll
    for (int q = 0; q < 2; q++)
#pragma unroll
        for (int j = 0; j < 4; j++) av[q][j] = 0.f;

    const int rem = vl - kc * 64;
    const int imax = rem <= 0 ? 0 : (rem > 64 ? 64 : rem);
#pragma unroll 2
    for (int i = 0; i < imax; i++) {
        const int k = kc * 64 + i;
        const float4 vv = *(const float4*)&vb[k * DV_];
        const float2 pp = *(const float2*)&sc[k][0];
        av[0][0] = fmaf(pp.x, vv.x, av[0][0]); av[0][1] = fmaf(pp.x, vv.y, av[0][1]);
        av[0][2] = fmaf(pp.x, vv.z, av[0][2]); av[0][3] = fmaf(pp.x, vv.w, av[0][3]);
        av[1][0] = fmaf(pp.y, vv.x, av[1][0]); av[1][1] = fmaf(pp.y, vv.y, av[1][1]);
        av[1][2] = fmaf(pp.y, vv.z, av[1][2]); av[1][3] = fmaf(pp.y, vv.w, av[1][3]);
    }
#pragma unroll
    for (int q = 0; q < 2; q++)
        *(float4*)&red[kc][q][vg] = make_float4(av[q][0], av[q][1], av[q][2], av[q][3]);
    __syncthreads();

    if (tid < 256) {
        const int q = tid >> 7, v = tid & 127;
        float tsum = 0.f;
#pragma unroll
        for (int g = 0; g < 16; g++) tsum += red[g][q][v];
        out[(b * Q_ + q0 + q) * DV_ + v] = tsum * rl[q];
    }
}

extern "C" void kernel_launch(void* const* d_in, const int* in_sizes, int n_in,
                              void* d_out, int out_size, void* d_ws, size_t ws_size,
                              hipStream_t stream) {
    const float* queries    = (const float*)d_in[0];  // [8,256,256]
    const float* keys       = (const float*)d_in[1];  // [8,1024,256]
    const float* values     = (const float*)d_in[2];  // [8,1024,128]
    const int*   valid_lens = (const int*)d_in[3];    // [8]
    const float* W_q        = (const float*)d_in[4];  // [256,128]
    const float* W_k        = (const float*)d_in[5];  // [256,128]
    const float* w_v        = (const float*)d_in[6];  // [128]
    float* out = (float*)d_out;

    float*  ws   = (float*)d_ws;
    float*  qE   = ws + QE_OFF;
    float2* kET2 = (float2*)(ws + KE_OFF);
    float*  wpk  = ws + WPK_OFF;

    proj_kernel<<<320, 256, 0, stream>>>(queries, keys, W_q, W_k, w_v, qE, kET2, wpk);
    attn_kernel<<<1024, 512, 0, stream>>>(qE, kET2, values, valid_lens, wpk, out);
}